// Round 7
// baseline (86.395 us; speedup 1.0000x reference)
//
#include <hip/hip_runtime.h>
#include <hip/hip_bf16.h>

// GroundPlane: RANSAC plane fit + signed distance map.
// B=4, points (B,3,H=384,W=1280) f32; rand_ind (B,125) i32.
// gH=192, N=gH*W=245760 (bottom-half cloud = tail rows of each channel, contiguous).
// Reference quirk: ps = tile(gp,(25,1,1)) => plane m=b*25+it is scored against
// point-batch (b+it)%4 (25 = 1 mod 4). Replicated here.
//
// R2: fixed scratch spill -> 210->93us. R4: fit folded into k_count -> 87us.
// R5: memset node + atomics removed -> 86.1us (PASS). R6: cooperative-kernel
// fusion FAILED under graph capture (launch silently dropped) -> reverted to
// the R5 structure. Floor analysis: harness 256MiB ws poison fill (~45us @75%
// HBM) + input restore + d_out poison are in the timed window; our k_count is
// f64-VALU-bound (~6us, f64 needed for argmax stability at the |d|<0.1
// boundary) and k_dist is HBM-bound at 31.5MB (~5us). This is the effective
// roofline for this harness.

constexpr int BN      = 4;
constexpr int H       = 384;
constexpr int W       = 1280;
constexpr int HW      = H * W;          // 491520
constexpr int GH      = 192;            // int(0.5*H)
constexpr int NPTS    = GH * W;         // 245760
constexpr int MAX_IT  = 25;
constexpr int NUM_PTS = 5;
constexpr int TOTAL_P = BN * MAX_IT;    // 100 planes

constexpr int NGRP         = 5;                    // plane-groups per point-batch
constexpr int GSZ          = 5;                    // planes per group
constexpr int CHUNKS       = 60;                   // chunks per (pb,grp)
constexpr int PSTRIDE      = 64;                   // partial-count row stride (pad)
constexpr int F4_PER_CHUNK = NPTS / 4 / CHUNKS;    // 1024 float4 per chunk
constexpr int ITERS        = F4_PER_CHUNK / 256;   // 4 float4 per thread
constexpr int BLOCKS_PER_B = (HW / 4) / 256;       // 480 (k_dist)

// ---- Kernel 1: fit (redundant per block, threads 0..4) + partial counts ----
__global__ __launch_bounds__(256) void k_count(
        const float* __restrict__ pts, const int* __restrict__ rind,
        float* __restrict__ wsf, int* __restrict__ partial) {
    __shared__ double swt[GSZ][3];
    __shared__ int    spid[GSZ];
    __shared__ int    sacc[GSZ];
    // grid: grp fastest, then pb, then chunk
    int grp   = blockIdx.x % NGRP;
    int pb    = (blockIdx.x / NGRP) % BN;
    int chunk = blockIdx.x / (NGRP * BN);
    int tid   = threadIdx.x;
    if (tid < GSZ) {
        sacc[tid] = 0;
        // enumerate planes (b,it) with (b+it)%4==pb; pick the (grp*GSZ+tid)-th
        int target = grp * GSZ + tid;
        int s = 0, pi = 0;
        for (int b = 0; b < BN; ++b) {
            int r = ((pb - b) % BN + BN) % BN;
            for (int it = r; it < MAX_IT; it += BN) {
                if (s == target) pi = b * MAX_IT + it;
                ++s;
            }
        }
        spid[tid] = pi;
        // --- fit plane pi from batch (pi/25)'s sampled points, f64 Cramer ---
        int fb = pi / MAX_IT, fit_it = pi % MAX_IT;
        const float* base = pts + (size_t)fb * 3 * HW + (size_t)(H - GH) * W;
        const int* ri = rind + fb * (MAX_IT * NUM_PTS) + fit_it * NUM_PTS;
        double Sxx = 0, Sxz = 0, Sx = 0, Szz = 0, Sz = 0, Sxy = 0, Szy = 0, Sy = 0;
#pragma unroll
        for (int p = 0; p < NUM_PTS; ++p) {
            int n = ri[p];
            double x = (double)base[n];
            double y = (double)base[HW + n];        // VAX=1 -> y is the "B" column
            double z = (double)base[2 * HW + n];
            Sxx += x * x; Sxz += x * z; Sx += x;
            Szz += z * z; Sz += z;
            Sxy += x * y; Szy += z * y; Sy += y;
        }
        const double e = 1e-6;   // AtA + 1e-6 broadcasts onto ALL nine entries
        double m00 = Sxx + e, m01 = Sxz + e, m02 = Sx + e;
        double m10 = Sxz + e, m11 = Szz + e, m12 = Sz + e;
        double m20 = Sx + e,  m21 = Sz + e,  m22 = (double)NUM_PTS + e;
        double v0 = Sxy, v1 = Szy, v2 = Sy;
        double det = m00 * (m11 * m22 - m12 * m21)
                   - m01 * (m10 * m22 - m12 * m20)
                   + m02 * (m10 * m21 - m11 * m20);
        double inv = 1.0 / det;
        double d0 = v0  * (m11 * m22 - m12 * m21)
                  - m01 * (v1  * m22 - m12 * v2 )
                  + m02 * (v1  * m21 - m11 * v2 );
        double d1 = m00 * (v1  * m22 - m12 * v2 )
                  - v0  * (m10 * m22 - m12 * m20)
                  + m02 * (m10 * v2  - v1  * m20);
        double d2 = m00 * (m11 * v2  - v1  * m21)
                  - m01 * (m10 * v2  - v1  * m20)
                  + v0  * (m10 * m21 - m11 * m20);
        double w0 = d0 * inv, w1 = d1 * inv, w2 = d2 * inv;
        swt[tid][0] = w0; swt[tid][1] = w1; swt[tid][2] = w2;
        if (chunk == 0) {   // publish f32 weights for k_dist (20 blocks cover all 100)
            wsf[pi * 3 + 0] = (float)w0;
            wsf[pi * 3 + 1] = (float)w1;
            wsf[pi * 3 + 2] = (float)w2;
        }
    }
    __syncthreads();
    // hoist weights to registers (15 f64)
    double wa0 = swt[0][0], wa1 = swt[0][1], wa2 = swt[0][2];
    double wb0 = swt[1][0], wb1 = swt[1][1], wb2 = swt[1][2];
    double wc0 = swt[2][0], wc1 = swt[2][1], wc2 = swt[2][2];
    double wd0 = swt[3][0], wd1 = swt[3][1], wd2 = swt[3][2];
    double we0 = swt[4][0], we1 = swt[4][1], we2 = swt[4][2];

    const float* base = pts + (size_t)pb * 3 * HW + (size_t)(H - GH) * W;
    const float4* px = (const float4*)base;
    const float4* py = (const float4*)(base + HW);
    const float4* pz = (const float4*)(base + 2 * HW);

    int a0 = 0, a1 = 0, a2 = 0, a3 = 0, a4 = 0;
#pragma unroll
    for (int it = 0; it < ITERS; ++it) {
        int f = chunk * F4_PER_CHUNK + it * 256 + tid;
        float4 x4 = px[f], y4 = py[f], z4 = pz[f];
#pragma unroll
        for (int e = 0; e < 4; ++e) {
            double x = (double)((const float*)&x4)[e];
            double y = (double)((const float*)&y4)[e];
            double z = (double)((const float*)&z4)[e];
            double nb = -y;   // d = x*w0 + z*w1 + (w2 - y)
            a0 += (fabs(fma(x, wa0, fma(z, wa1, wa2 + nb))) < 0.1) ? 1 : 0;
            a1 += (fabs(fma(x, wb0, fma(z, wb1, wb2 + nb))) < 0.1) ? 1 : 0;
            a2 += (fabs(fma(x, wc0, fma(z, wc1, wc2 + nb))) < 0.1) ? 1 : 0;
            a3 += (fabs(fma(x, wd0, fma(z, wd1, wd2 + nb))) < 0.1) ? 1 : 0;
            a4 += (fabs(fma(x, we0, fma(z, we1, we2 + nb))) < 0.1) ? 1 : 0;
        }
    }
    // wave reduce -> LDS block reduce -> ONE plain store per plane per block
    // (partial[pi][chunk] is written by exactly one block: race-free, no init)
    int vals[GSZ] = {a0, a1, a2, a3, a4};
#pragma unroll
    for (int j = 0; j < GSZ; ++j) {
        int v = vals[j];
        for (int off = 32; off > 0; off >>= 1) v += __shfl_down(v, off, 64);
        if ((tid & 63) == 0) atomicAdd(&sacc[j], v);
    }
    __syncthreads();
    if (tid < GSZ) partial[spid[tid] * PSTRIDE + chunk] = sacc[tid];
}

// -- Kernel 2: per-batch partial-sum + argmax (redundant, L2-hot) + dist map --
__global__ __launch_bounds__(256) void k_dist(
        const float* __restrict__ pts, const float* __restrict__ wsf,
        const int* __restrict__ partial, float* __restrict__ out) {
    __shared__ int   scnt[MAX_IT];
    __shared__ float sw[3];
    int b   = blockIdx.x / BLOCKS_PER_B;
    int blk = blockIdx.x % BLOCKS_PER_B;
    int tid = threadIdx.x;
    if (tid < MAX_IT) {   // thread t sums plane (b,t)'s 60 chunk-partials
        const int* p = partial + (b * MAX_IT + tid) * PSTRIDE;
        int s = 0;
#pragma unroll
        for (int c = 0; c < CHUNKS; ++c) s += p[c];
        scnt[tid] = s;
    }
    __syncthreads();
    if (tid == 0) {
        int best = 0, bc = scnt[0];
        for (int it = 1; it < MAX_IT; ++it) {
            int c = scnt[it];
            if (c > bc) { bc = c; best = it; }   // strict > : first-max == np argmax
        }
        int pi = b * MAX_IT + best;
        sw[0] = wsf[pi * 3 + 0];
        sw[1] = wsf[pi * 3 + 1];
        sw[2] = wsf[pi * 3 + 2];
        if (blk == 0) {   // best_w tail: (B,3,1) = 12 floats
            out[(size_t)BN * HW + b * 3 + 0] = sw[0];
            out[(size_t)BN * HW + b * 3 + 1] = sw[1];
            out[(size_t)BN * HW + b * 3 + 2] = sw[2];
        }
    }
    __syncthreads();
    float w0 = sw[0], w1 = sw[1], w2 = sw[2];
    const float4* px = (const float4*)(pts + (size_t)b * 3 * HW);
    const float4* py = px + HW / 4;
    const float4* pz = py + HW / 4;
    int i = blk * 256 + tid;   // element in [0, HW/4)
    float4 x = px[i], y = py[i], z = pz[i];
    float4 r;
    r.x = w0 * x.x + w1 * z.x + w2 - y.x;
    r.y = w0 * x.y + w1 * z.y + w2 - y.y;
    r.z = w0 * x.z + w1 * z.z + w2 - y.z;
    r.w = w0 * x.w + w1 * z.w + w2 - y.w;
    ((float4*)(out + (size_t)b * HW))[i] = r;
}

extern "C" void kernel_launch(void* const* d_in, const int* in_sizes, int n_in,
                              void* d_out, int out_size, void* d_ws, size_t ws_size,
                              hipStream_t stream) {
    const float* pts  = (const float*)d_in[0];
    const int*   rind = (const int*)d_in[1];
    float* out = (float*)d_out;

    float* wsf     = (float*)d_ws;                  // 300 floats
    int*   partial = (int*)(wsf + TOTAL_P * 3 + 4); // 100*64 ints (each slot
                                                    // written before read; no init)

    k_count<<<NGRP * BN * CHUNKS, 256, 0, stream>>>(pts, rind, wsf, partial);
    k_dist <<<BN * BLOCKS_PER_B, 256, 0, stream>>>(pts, wsf, partial, out);
}